// Round 1
// baseline (304.973 us; speedup 1.0000x reference)
//
#include <hip/hip_runtime.h>
#include <hip/hip_bf16.h>

#define TPB 256

constexpr int B_    = 262144;
constexpr int WIN_  = 5;
constexpr int VOCAB_= 100000;
constexpr int EMB_  = 50;
constexpr int HID_  = 250;   // real K and hidden width
constexpr int OUT_  = 36;
constexpr int KP    = 256;   // padded K (WIN*EMB and HID padded)
constexpr int NP    = 256;   // padded hidden
constexpr int OP    = 48;    // padded out cols (3 x 16)
constexpr int BM    = 64;    // rows per block
constexpr int XS    = 264;   // LDS row stride (bf16 elems) for x/h tile: 528B -> 2-way free
constexpr int WSRD  = 40;    // LDS row stride for W1 chunk: 80B -> 2-way free, 16B-aligned

typedef __attribute__((ext_vector_type(8))) short fragA;  // 8 bf16 in 4 VGPRs
typedef __attribute__((ext_vector_type(4))) float fragC;  // 4 f32 acc

__device__ __forceinline__ unsigned short f2b(float f) {
    union { float f; unsigned int u; } x; x.f = f;
    unsigned int r = (x.u + 0x7fffu + ((x.u >> 16) & 1u)) >> 16;  // RNE
    return (unsigned short)r;
}

// Convert W1 -> wT[n][k] bf16 (256x256, zero-padded), W2 -> woT[o][k] bf16 (48x256)
__global__ void prep_weights(const float* __restrict__ w_in,
                             const float* __restrict__ w_out,
                             short* __restrict__ wT,
                             short* __restrict__ woT) {
    int id = blockIdx.x * blockDim.x + threadIdx.x;
    if (id < NP * KP) {
        int n = id >> 8, k = id & 255;
        float v = (n < HID_ && k < HID_) ? w_in[k * HID_ + n] : 0.f;
        wT[id] = (short)f2b(v);
    } else {
        int id2 = id - NP * KP;
        if (id2 < OP * KP) {
            int o = id2 >> 8, k = id2 & 255;
            float v = (o < OUT_ && k < HID_) ? w_out[k * OUT_ + o] : 0.f;
            woT[id2] = (short)f2b(v);
        }
    }
}

__launch_bounds__(TPB, 2)
__global__ void tagger_main(const int* __restrict__ idx,
                            const float* __restrict__ emb,
                            const float* __restrict__ b_in,
                            const float* __restrict__ b_out,
                            const short* __restrict__ wT,
                            const short* __restrict__ woT,
                            float* __restrict__ out) {
    __shared__ short xs[BM * XS];      // x tile, later reused as h tile (33792 B)
    __shared__ short wc[NP * WSRD];    // staged W1 K-chunk (20480 B)
    __shared__ int   sidx[BM * WIN_];  // 1280 B

    const int tid   = threadIdx.x;
    const int lane  = tid & 63;
    const int wave  = tid >> 6;
    const int l16   = lane & 15;
    const int khalf = lane >> 4;       // 0..3, selects k sub-block of 8
    const int r0    = blockIdx.x * BM;

    // ---- load indices ----
    for (int i = tid; i < BM * WIN_; i += TPB) sidx[i] = idx[r0 * WIN_ + i];
    __syncthreads();

    // ---- gather + mask + bf16 convert: thread t owns column k=t for all 64 rows ----
    {
        const int k = tid;
        int w_ = 0, e_ = 0;
        const bool kv = (k < HID_);
        if (kv) { w_ = k / EMB_; e_ = k - w_ * EMB_; }
        for (int r = 0; r < BM; ++r) {
            float v = 0.f;
            if (kv) {
                int iv = sidx[r * WIN_ + w_];
                if (iv >= 0 && iv < VOCAB_) v = emb[iv * EMB_ + e_];
            }
            xs[r * XS + k] = (short)f2b(v);
        }
    }
    __syncthreads();

    // ---- layer 1: [64 x 256] x [256 x 256], each wave owns 64 rows x 64 cols ----
    fragC acc[4][4];
    #pragma unroll
    for (int mf = 0; mf < 4; ++mf)
        #pragma unroll
        for (int nf = 0; nf < 4; ++nf)
            acc[mf][nf] = (fragC){0.f, 0.f, 0.f, 0.f};

    const int nb   = wave * 64;
    const int nrow = tid >> 3, sub = tid & 7;

    for (int kk = 0; kk < KP; kk += 32) {
        // stage wT[:, kk:kk+32] into LDS: 8B per thread x 8 iters (coalesced 64B runs)
        const ushort4* gsrc = (const ushort4*)wT;
        #pragma unroll
        for (int it = 0; it < 8; ++it) {
            int n = it * 32 + nrow;
            ushort4 v = gsrc[n * (KP / 4) + (kk >> 2) + sub];
            *(ushort4*)&wc[n * WSRD + sub * 4] = v;
        }
        __syncthreads();

        fragA a[4], b[4];
        #pragma unroll
        for (int mf = 0; mf < 4; ++mf)
            a[mf] = *(const fragA*)&xs[(mf * 16 + l16) * XS + kk + khalf * 8];
        #pragma unroll
        for (int nf = 0; nf < 4; ++nf)
            b[nf] = *(const fragA*)&wc[(nb + nf * 16 + l16) * WSRD + khalf * 8];
        #pragma unroll
        for (int mf = 0; mf < 4; ++mf)
            #pragma unroll
            for (int nf = 0; nf < 4; ++nf)
                acc[mf][nf] = __builtin_amdgcn_mfma_f32_16x16x32_bf16(a[mf], b[nf], acc[mf][nf], 0, 0, 0);
        __syncthreads();  // wc reads done before next stage; last iter: xs reads done
    }

    // ---- epilogue 1: bias + tanh -> h (bf16) back into xs ----
    #pragma unroll
    for (int nf = 0; nf < 4; ++nf) {
        int col = nb + nf * 16 + l16;
        float bi = (col < HID_) ? b_in[col] : 0.f;
        #pragma unroll
        for (int mf = 0; mf < 4; ++mf) {
            #pragma unroll
            for (int j = 0; j < 4; ++j) {
                int row = mf * 16 + khalf * 4 + j;
                float h = tanhf(acc[mf][nf][j] + bi);
                xs[row * XS + col] = (short)f2b(h);
            }
        }
    }
    __syncthreads();

    // ---- layer 2: [64 x 256] x [256 x 48]; each wave owns 16 rows x 48 cols ----
    fragC acc2[3];
    #pragma unroll
    for (int of = 0; of < 3; ++of) acc2[of] = (fragC){0.f, 0.f, 0.f, 0.f};

    for (int kk = 0; kk < KP; kk += 32) {
        fragA ha = *(const fragA*)&xs[(wave * 16 + l16) * XS + kk + khalf * 8];
        #pragma unroll
        for (int of = 0; of < 3; ++of) {
            fragA wb = *(const fragA*)&woT[(of * 16 + l16) * KP + kk + khalf * 8];
            acc2[of] = __builtin_amdgcn_mfma_f32_16x16x32_bf16(ha, wb, acc2[of], 0, 0, 0);
        }
    }

    // ---- epilogue 2: bias + store f32 ----
    #pragma unroll
    for (int of = 0; of < 3; ++of) {
        int o = of * 16 + l16;
        if (o < OUT_) {
            float bo = b_out[o];
            #pragma unroll
            for (int j = 0; j < 4; ++j) {
                int row = r0 + wave * 16 + khalf * 4 + j;
                out[row * OUT_ + o] = acc2[of][j] + bo;
            }
        }
    }
}

extern "C" void kernel_launch(void* const* d_in, const int* in_sizes, int n_in,
                              void* d_out, int out_size, void* d_ws, size_t ws_size,
                              hipStream_t stream) {
    const int*   idx   = (const int*)d_in[0];
    const float* emb   = (const float*)d_in[1];
    const float* w_in  = (const float*)d_in[2];
    const float* b_in  = (const float*)d_in[3];
    const float* w_out = (const float*)d_in[4];
    const float* b_out = (const float*)d_in[5];
    float* out = (float*)d_out;

    short* wT  = (short*)d_ws;          // 256*256 bf16 = 128 KiB
    short* woT = wT + NP * KP;          // 48*256  bf16 =  24 KiB

    int prep_threads = NP * KP + OP * KP;  // 77824 = 304 * 256
    prep_weights<<<(prep_threads + TPB - 1) / TPB, TPB, 0, stream>>>(w_in, w_out, wT, woT);
    tagger_main<<<B_ / BM, TPB, 0, stream>>>(idx, emb, b_in, b_out, wT, woT, out);
}

// Round 3
// 171.929 us; speedup vs baseline: 1.7738x; 1.7738x over previous
//
#include <hip/hip_runtime.h>
#include <hip/hip_bf16.h>

#define TPB 256

constexpr int B_    = 262144;
constexpr int WIN_  = 5;
constexpr int VOCAB_= 100000;
constexpr int EMB_  = 50;
constexpr int HID_  = 250;   // real K and hidden width
constexpr int OUT_  = 36;
constexpr int KP    = 256;   // padded K (WIN*EMB and HID padded)
constexpr int NP    = 256;   // padded hidden
constexpr int OP    = 48;    // padded out cols (3 x 16)
constexpr int BM    = 64;    // rows per block
constexpr int XS    = 264;   // LDS row stride (bf16 elems): 528B -> 2-way (free)

typedef __attribute__((ext_vector_type(8))) short fragA;  // 8 bf16 in 4 VGPRs
typedef __attribute__((ext_vector_type(4))) float fragC;  // 4 f32 acc

__device__ __forceinline__ unsigned short f2b(float f) {
    union { float f; unsigned int u; } x; x.f = f;
    unsigned int r = (x.u + 0x7fffu + ((x.u >> 16) & 1u)) >> 16;  // RNE
    return (unsigned short)r;
}

__device__ __forceinline__ float fast_tanh(float x) {
    // tanh(x) = 1 - 2/(e^{2x}+1); ~1e-7 rel err -> far below bf16 quantum
    float e = __expf(2.f * x);
    return 1.f - __fdividef(2.f, e + 1.f);
}

// Convert W1 -> wT[n][k] bf16 (256x256, zero-padded), W2 -> woT[o][k] bf16 (48x256)
__global__ void prep_weights(const float* __restrict__ w_in,
                             const float* __restrict__ w_out,
                             short* __restrict__ wT,
                             short* __restrict__ woT) {
    int id = blockIdx.x * blockDim.x + threadIdx.x;
    if (id < NP * KP) {
        int n = id >> 8, k = id & 255;
        float v = (n < HID_ && k < HID_) ? w_in[k * HID_ + n] : 0.f;
        wT[id] = (short)f2b(v);
    } else {
        int id2 = id - NP * KP;
        if (id2 < OP * KP) {
            int o = id2 >> 8, k = id2 & 255;
            float v = (o < OUT_ && k < HID_) ? w_out[k * OUT_ + o] : 0.f;
            woT[id2] = (short)f2b(v);
        }
    }
}

__launch_bounds__(TPB, 4)
__global__ void tagger_main(const int* __restrict__ idx,
                            const float* __restrict__ emb,
                            const float* __restrict__ b_in,
                            const float* __restrict__ b_out,
                            const short* __restrict__ wT,
                            const short* __restrict__ woT,
                            float* __restrict__ out) {
    __shared__ short xs[BM * XS];      // x tile, later reused as h tile (33792 B)
    __shared__ int   sidx[BM * WIN_];  // 1280 B

    const int tid   = threadIdx.x;
    const int lane  = tid & 63;
    const int wave  = tid >> 6;
    const int l16   = lane & 15;
    const int khalf = lane >> 4;       // 0..3, selects k sub-block of 8
    const int r0    = blockIdx.x * BM;

    // ---- load indices ----
    for (int i = tid; i < BM * WIN_; i += TPB) sidx[i] = idx[r0 * WIN_ + i];
    __syncthreads();

    // ---- gather: 4 threads per (row,win) pair; 7 independent float2 loads each ----
    {
        const int sub = tid & 3;
        #pragma unroll
        for (int it = 0; it < 5; ++it) {
            int p   = it * 64 + (tid >> 2);       // pair 0..319
            int row = p / 5;                      // magic-mul div
            int win = p - row * 5;
            int iv  = sidx[p];
            bool valid = (iv >= 0 && iv < VOCAB_);
            const float* base = emb + (long long)(valid ? iv : 0) * EMB_;
            #pragma unroll
            for (int j = 0; j < 7; ++j) {
                int c = sub + 4 * j;              // float2 chunk 0..24
                if (c < 25) {
                    float2 v = make_float2(0.f, 0.f);
                    if (valid) v = *(const float2*)(base + 2 * c);
                    unsigned pk = (unsigned)f2b(v.x) | ((unsigned)f2b(v.y) << 16);
                    *(unsigned*)&xs[row * XS + win * 50 + 2 * c] = pk;
                }
            }
        }
        // zero-fill pad columns 250..255 (K padding) -- MFMA sums all 256 k's;
        // uninitialized LDS here can be NaN and NaN*0 poisons every output (R2 bug)
        if (tid < 192) {
            int row = tid / 3, c = tid - row * 3;
            *(unsigned*)&xs[row * XS + 250 + 2 * c] = 0u;
        }
    }
    __syncthreads();

    // ---- layer 1: [64 x 256] x [256 x 256]; wave owns 64 rows x 64 cols.
    //      B-fragments loaded JIT from global (L2-resident wT) -> no barriers, no LDS staging.
    fragC acc[4][4];
    #pragma unroll
    for (int mf = 0; mf < 4; ++mf)
        #pragma unroll
        for (int nf = 0; nf < 4; ++nf)
            acc[mf][nf] = (fragC){0.f, 0.f, 0.f, 0.f};

    const int nb = wave * 64;

    #pragma unroll 2
    for (int kk = 0; kk < 8; ++kk) {
        fragA a[4], b[4];
        #pragma unroll
        for (int mf = 0; mf < 4; ++mf)
            a[mf] = *(const fragA*)&xs[(mf * 16 + l16) * XS + kk * 32 + khalf * 8];
        #pragma unroll
        for (int nf = 0; nf < 4; ++nf)
            b[nf] = *(const fragA*)&wT[(nb + nf * 16 + l16) * KP + kk * 32 + khalf * 8];
        #pragma unroll
        for (int mf = 0; mf < 4; ++mf)
            #pragma unroll
            for (int nf = 0; nf < 4; ++nf)
                acc[mf][nf] = __builtin_amdgcn_mfma_f32_16x16x32_bf16(a[mf], b[nf], acc[mf][nf], 0, 0, 0);
    }

    __syncthreads();  // all xs (x) reads complete before overwriting with h

    // ---- epilogue 1: bias + tanh -> h (bf16) back into xs ----
    #pragma unroll
    for (int nf = 0; nf < 4; ++nf) {
        int col = nb + nf * 16 + l16;
        float bi = (col < HID_) ? b_in[col] : 0.f;
        #pragma unroll
        for (int mf = 0; mf < 4; ++mf) {
            #pragma unroll
            for (int j = 0; j < 4; ++j) {
                int row = mf * 16 + khalf * 4 + j;
                float h = fast_tanh(acc[mf][nf][j] + bi);
                xs[row * XS + col] = (short)f2b(h);
            }
        }
    }
    __syncthreads();

    // ---- layer 2: [64 x 256] x [256 x 48]; each wave owns 16 rows x 48 cols ----
    fragC acc2[3];
    #pragma unroll
    for (int of = 0; of < 3; ++of) acc2[of] = (fragC){0.f, 0.f, 0.f, 0.f};

    #pragma unroll 2
    for (int kk = 0; kk < 8; ++kk) {
        fragA ha = *(const fragA*)&xs[(wave * 16 + l16) * XS + kk * 32 + khalf * 8];
        #pragma unroll
        for (int of = 0; of < 3; ++of) {
            fragA wb = *(const fragA*)&woT[(of * 16 + l16) * KP + kk * 32 + khalf * 8];
            acc2[of] = __builtin_amdgcn_mfma_f32_16x16x32_bf16(ha, wb, acc2[of], 0, 0, 0);
        }
    }

    // ---- epilogue 2: bias + store f32 ----
    #pragma unroll
    for (int of = 0; of < 3; ++of) {
        int o = of * 16 + l16;
        if (o < OUT_) {
            float bo = b_out[o];
            #pragma unroll
            for (int j = 0; j < 4; ++j) {
                int row = r0 + wave * 16 + khalf * 4 + j;
                out[row * OUT_ + o] = acc2[of][j] + bo;
            }
        }
    }
}

extern "C" void kernel_launch(void* const* d_in, const int* in_sizes, int n_in,
                              void* d_out, int out_size, void* d_ws, size_t ws_size,
                              hipStream_t stream) {
    const int*   idx   = (const int*)d_in[0];
    const float* emb   = (const float*)d_in[1];
    const float* w_in  = (const float*)d_in[2];
    const float* b_in  = (const float*)d_in[3];
    const float* w_out = (const float*)d_in[4];
    const float* b_out = (const float*)d_in[5];
    float* out = (float*)d_out;

    short* wT  = (short*)d_ws;          // 256*256 bf16 = 128 KiB
    short* woT = wT + NP * KP;          // 48*256  bf16 =  24 KiB

    int prep_threads = NP * KP + OP * KP;  // 77824 = 304 * 256
    prep_weights<<<(prep_threads + TPB - 1) / TPB, TPB, 0, stream>>>(w_in, w_out, wT, woT);
    tagger_main<<<B_ / BM, TPB, 0, stream>>>(idx, emb, b_in, b_out, wT, woT, out);
}